// Round 2
// baseline (76.951 us; speedup 1.0000x reference)
//
#include <hip/hip_runtime.h>
#include <math.h>

#define DEPTH 5

// One thread handles 4 samples: two float4 loads of x (x0,x1 interleaved),
// one float4 store of the sigmoid outputs.
//
// Circuit simplification: after the per-sample RY embedding the state is the
// real product vector p=(c0c1, c0s1, s0c1, s0s1). The 5 RX+CNOT layers form a
// sample-independent 4x4 complex unitary U (depends only on q_weights), built
// once per block by thread 0 into LDS. <Z0> = +|psi0|^2+|psi1|^2-|psi2|^2-|psi3|^2
// with psi = U*p, then sigmoid(z*w + b).
__global__ __launch_bounds__(256) void hqnet_kernel(
    const float* __restrict__ x, const float* __restrict__ qw,
    const float* __restrict__ fcw, const float* __restrict__ fcb,
    float* __restrict__ out, int n_samples)
{
    __shared__ float uRe[4][4], uIm[4][4];
    __shared__ float s_w, s_b;

    if (threadIdx.x == 0) {
        float re[4][4], im[4][4];
        #pragma unroll
        for (int i = 0; i < 4; i++)
            for (int j = 0; j < 4; j++) { re[i][j] = (i == j) ? 1.f : 0.f; im[i][j] = 0.f; }
        for (int l = 0; l < DEPTH; l++) {
            float c0, s0, c1, s1;
            sincosf(qw[2 * l + 0] * 0.5f, &s0, &c0);
            sincosf(qw[2 * l + 1] * 0.5f, &s1, &c1);
            // RX on wire 0 (index pairs (b, 2+b)): [a';b'] = [c a - i s b ; -i s a + c b]
            for (int b = 0; b < 2; b++) {
                int r0 = b, r1 = 2 + b;
                for (int j = 0; j < 4; j++) {
                    float ar = re[r0][j], ai = im[r0][j], br = re[r1][j], bi = im[r1][j];
                    re[r0][j] = c0 * ar + s0 * bi;  im[r0][j] = c0 * ai - s0 * br;
                    re[r1][j] = c0 * br + s0 * ai;  im[r1][j] = c0 * bi - s0 * ar;
                }
            }
            // RX on wire 1 (index pairs (2a, 2a+1))
            for (int a = 0; a < 2; a++) {
                int r0 = 2 * a, r1 = 2 * a + 1;
                for (int j = 0; j < 4; j++) {
                    float ar = re[r0][j], ai = im[r0][j], br = re[r1][j], bi = im[r1][j];
                    re[r0][j] = c1 * ar + s1 * bi;  im[r0][j] = c1 * ai - s1 * br;
                    re[r1][j] = c1 * br + s1 * ai;  im[r1][j] = c1 * bi - s1 * ar;
                }
            }
            // CNOT(0->1): swap basis states |10> and |11> (rows 2,3)
            for (int j = 0; j < 4; j++) {
                float tr = re[2][j], ti = im[2][j];
                re[2][j] = re[3][j]; im[2][j] = im[3][j];
                re[3][j] = tr;       im[3][j] = ti;
            }
        }
        #pragma unroll
        for (int i = 0; i < 4; i++)
            for (int j = 0; j < 4; j++) { uRe[i][j] = re[i][j]; uIm[i][j] = im[i][j]; }
        s_w = fcw[0];
        s_b = fcb[0];
    }
    __syncthreads();

    // Broadcast U + fc params from LDS (same-address reads: conflict-free)
    float ur[4][4], ui[4][4];
    #pragma unroll
    for (int i = 0; i < 4; i++)
        #pragma unroll
        for (int j = 0; j < 4; j++) { ur[i][j] = uRe[i][j]; ui[i][j] = uIm[i][j]; }
    const float w = s_w, bb = s_b;

    const int t = blockIdx.x * blockDim.x + threadIdx.x;
    const int base = t * 4;
    if (base >= n_samples) return;

    if (base + 3 < n_samples) {
        const float4* xv = (const float4*)x;
        float4 a  = xv[2 * t];
        float4 b4 = xv[2 * t + 1];
        float xs[8] = {a.x, a.y, a.z, a.w, b4.x, b4.y, b4.z, b4.w};
        float res[4];
        #pragma unroll
        for (int k = 0; k < 4; k++) {
            float s0, c0, s1, c1;
            __sincosf(xs[2 * k + 0] * 0.5f, &s0, &c0);
            __sincosf(xs[2 * k + 1] * 0.5f, &s1, &c1);
            const float p0 = c0 * c1, p1 = c0 * s1, p2 = s0 * c1, p3 = s0 * s1;
            float z = 0.f;
            #pragma unroll
            for (int i = 0; i < 4; i++) {
                float vr = ur[i][0] * p0 + ur[i][1] * p1 + ur[i][2] * p2 + ur[i][3] * p3;
                float vi = ui[i][0] * p0 + ui[i][1] * p1 + ui[i][2] * p2 + ui[i][3] * p3;
                float pr = vr * vr + vi * vi;
                z += (i < 2) ? pr : -pr;
            }
            res[k] = 1.0f / (1.0f + __expf(-(z * w + bb)));
        }
        ((float4*)out)[t] = make_float4(res[0], res[1], res[2], res[3]);
    } else {
        // scalar tail (not hit for N = 2^21, kept for safety)
        for (int k = 0; k < 4 && base + k < n_samples; k++) {
            float s0, c0, s1, c1;
            __sincosf(x[2 * (base + k) + 0] * 0.5f, &s0, &c0);
            __sincosf(x[2 * (base + k) + 1] * 0.5f, &s1, &c1);
            const float p0 = c0 * c1, p1 = c0 * s1, p2 = s0 * c1, p3 = s0 * s1;
            float z = 0.f;
            for (int i = 0; i < 4; i++) {
                float vr = ur[i][0] * p0 + ur[i][1] * p1 + ur[i][2] * p2 + ur[i][3] * p3;
                float vi = ui[i][0] * p0 + ui[i][1] * p1 + ui[i][2] * p2 + ui[i][3] * p3;
                float pr = vr * vr + vi * vi;
                z += (i < 2) ? pr : -pr;
            }
            out[base + k] = 1.0f / (1.0f + __expf(-(z * w + bb)));
        }
    }
}

extern "C" void kernel_launch(void* const* d_in, const int* in_sizes, int n_in,
                              void* d_out, int out_size, void* d_ws, size_t ws_size,
                              hipStream_t stream) {
    const float* x   = (const float*)d_in[0];  // [N,2]
    const float* qw  = (const float*)d_in[1];  // [5,2]
    const float* fcw = (const float*)d_in[2];  // [1,1]
    const float* fcb = (const float*)d_in[3];  // [1]
    float* out = (float*)d_out;                // [N]

    const int n_samples = in_sizes[0] / 2;
    const int n_threads = (n_samples + 3) / 4;
    const int block = 256;
    const int grid = (n_threads + block - 1) / block;
    hqnet_kernel<<<grid, block, 0, stream>>>(x, qw, fcw, fcb, out, n_samples);
}

// Round 3
// 73.532 us; speedup vs baseline: 1.0465x; 1.0465x over previous
//
#include <hip/hip_runtime.h>
#include <math.h>

#define DEPTH 5
#define SPT 8  // samples per thread

// Per-sample: state after RY embedding is the real product vector
// p=(c0c1, c0s1, s0c1, s0s1). The 5 RX+CNOT layers are a sample-independent
// 4x4 complex unitary U (weights only). <Z0> = |psi0|^2+|psi1|^2-|psi2|^2-|psi3|^2,
// psi = U p, then sigmoid(z*w+b).
//
// U is built cooperatively: lanes 0..3 each propagate basis vector e_j through
// the 5 layers (~160 FMA + 10 __sincosf each, wave-parallel) into LDS.
// Previous version had thread 0 do this serially with precise sincosf
// (~1.5-2 kcycles serialized per block) — that was the preamble bottleneck.
__global__ __launch_bounds__(256) void hqnet_kernel(
    const float* __restrict__ x, const float* __restrict__ qw,
    const float* __restrict__ fcw, const float* __restrict__ fcb,
    float* __restrict__ out, int n_samples)
{
    __shared__ float uRe[4][4], uIm[4][4];
    __shared__ float s_w, s_b;

    if (threadIdx.x < 4) {
        const int j = threadIdx.x;
        float cr[4], ci[4];
        #pragma unroll
        for (int i = 0; i < 4; i++) { cr[i] = (i == j) ? 1.f : 0.f; ci[i] = 0.f; }
        #pragma unroll
        for (int l = 0; l < DEPTH; l++) {
            float c0, s0, c1, s1;
            __sincosf(qw[2 * l + 0] * 0.5f, &s0, &c0);  // args in [0, pi]
            __sincosf(qw[2 * l + 1] * 0.5f, &s1, &c1);
            // RX wire 0: pairs (0,2),(1,3): a' = c a - i s b ; b' = -i s a + c b
            #pragma unroll
            for (int b = 0; b < 2; b++) {
                float ar = cr[b], ai = ci[b], br = cr[b + 2], bi = ci[b + 2];
                cr[b]     = c0 * ar + s0 * bi;  ci[b]     = c0 * ai - s0 * br;
                cr[b + 2] = c0 * br + s0 * ai;  ci[b + 2] = c0 * bi - s0 * ar;
            }
            // RX wire 1: pairs (0,1),(2,3)
            #pragma unroll
            for (int a = 0; a < 2; a++) {
                int r0 = 2 * a, r1 = 2 * a + 1;
                float ar = cr[r0], ai = ci[r0], br = cr[r1], bi = ci[r1];
                cr[r0] = c1 * ar + s1 * bi;  ci[r0] = c1 * ai - s1 * br;
                cr[r1] = c1 * br + s1 * ai;  ci[r1] = c1 * bi - s1 * ar;
            }
            // CNOT(0->1): swap basis states |10>,|11>
            float tr = cr[2], ti = ci[2];
            cr[2] = cr[3]; ci[2] = ci[3];
            cr[3] = tr;    ci[3] = ti;
        }
        #pragma unroll
        for (int i = 0; i < 4; i++) { uRe[i][j] = cr[i]; uIm[i][j] = ci[i]; }
        if (j == 0) { s_w = fcw[0]; s_b = fcb[0]; }
    }
    __syncthreads();

    // Broadcast U + fc params (same-address LDS reads: conflict-free)
    float ur[4][4], ui[4][4];
    #pragma unroll
    for (int i = 0; i < 4; i++)
        #pragma unroll
        for (int j = 0; j < 4; j++) { ur[i][j] = uRe[i][j]; ui[i][j] = uIm[i][j]; }
    const float w = s_w, bb = s_b;

    const int t = blockIdx.x * blockDim.x + threadIdx.x;
    const long long base = (long long)t * SPT;
    if (base >= n_samples) return;

    if (base + SPT <= n_samples) {
        const float4* xv = (const float4*)x;  // x is [N,2]: 1 float4 = 2 samples
        float xs[2 * SPT];
        #pragma unroll
        for (int q = 0; q < SPT / 2; q++) {
            float4 v = xv[(SPT / 2) * t + q];
            xs[4 * q + 0] = v.x; xs[4 * q + 1] = v.y;
            xs[4 * q + 2] = v.z; xs[4 * q + 3] = v.w;
        }
        float res[SPT];
        #pragma unroll
        for (int k = 0; k < SPT; k++) {
            float s0, c0, s1, c1;
            __sincosf(xs[2 * k + 0] * 0.5f, &s0, &c0);
            __sincosf(xs[2 * k + 1] * 0.5f, &s1, &c1);
            const float p0 = c0 * c1, p1 = c0 * s1, p2 = s0 * c1, p3 = s0 * s1;
            float zp = 0.f, zn = 0.f;
            #pragma unroll
            for (int i = 0; i < 4; i++) {
                float vr = ur[i][0] * p0 + ur[i][1] * p1 + ur[i][2] * p2 + ur[i][3] * p3;
                float vi = ui[i][0] * p0 + ui[i][1] * p1 + ui[i][2] * p2 + ui[i][3] * p3;
                float pr = vr * vr + vi * vi;
                if (i < 2) zp += pr; else zn += pr;
            }
            res[k] = 1.0f / (1.0f + __expf(-(w * zp - w * zn + bb)));
        }
        float4* ov = (float4*)out;
        #pragma unroll
        for (int q = 0; q < SPT / 4; q++)
            ov[(SPT / 4) * t + q] = make_float4(res[4 * q], res[4 * q + 1],
                                                res[4 * q + 2], res[4 * q + 3]);
    } else {
        // scalar tail (not hit for N = 2^21)
        for (int k = 0; k < SPT && base + k < n_samples; k++) {
            float s0, c0, s1, c1;
            __sincosf(x[2 * (base + k) + 0] * 0.5f, &s0, &c0);
            __sincosf(x[2 * (base + k) + 1] * 0.5f, &s1, &c1);
            const float p0 = c0 * c1, p1 = c0 * s1, p2 = s0 * c1, p3 = s0 * s1;
            float z = 0.f;
            for (int i = 0; i < 4; i++) {
                float vr = ur[i][0] * p0 + ur[i][1] * p1 + ur[i][2] * p2 + ur[i][3] * p3;
                float vi = ui[i][0] * p0 + ui[i][1] * p1 + ui[i][2] * p2 + ui[i][3] * p3;
                float pr = vr * vr + vi * vi;
                z += (i < 2) ? pr : -pr;
            }
            out[base + k] = 1.0f / (1.0f + __expf(-(z * w + bb)));
        }
    }
}

extern "C" void kernel_launch(void* const* d_in, const int* in_sizes, int n_in,
                              void* d_out, int out_size, void* d_ws, size_t ws_size,
                              hipStream_t stream) {
    const float* x   = (const float*)d_in[0];  // [N,2]
    const float* qw  = (const float*)d_in[1];  // [5,2]
    const float* fcw = (const float*)d_in[2];  // [1,1]
    const float* fcb = (const float*)d_in[3];  // [1]
    float* out = (float*)d_out;                // [N]

    const int n_samples = in_sizes[0] / 2;
    const int n_threads = (n_samples + SPT - 1) / SPT;
    const int block = 256;
    const int grid = (n_threads + block - 1) / block;
    hqnet_kernel<<<grid, block, 0, stream>>>(x, qw, fcw, fcb, out, n_samples);
}